// Round 15
// baseline (254.893 us; speedup 1.0000x reference)
//
#include <hip/hip_runtime.h>
#include <hip/hip_bf16.h>
#include <math.h>

// ---------- types ----------
typedef __bf16 bf16x8 __attribute__((ext_vector_type(8)));
typedef float  f32x4  __attribute__((ext_vector_type(4)));

#define B_ROWS 8192
#define HSZ    1024

#define GLOAD16(gsrc, ldst)                                                          \
  __builtin_amdgcn_global_load_lds((const __attribute__((address_space(1))) void*)(gsrc), \
                                   (__attribute__((address_space(3))) void*)(ldst),  \
                                   16, 0, 0)

__device__ inline unsigned short f2bf(float f) {
  union { float f; unsigned u; } x; x.f = f;
  unsigned r = x.u + 0x7fffu + ((x.u >> 16) & 1u);   // RNE
  return (unsigned short)(r >> 16);
}

__device__ inline float sigm(float x) { return 1.0f / (1.0f + __expf(-x)); }

// ---------- kernel 0: fp32 -> bf16 conversion + T precompute (16B stores) ----------
__global__ void k_convert(const float* __restrict__ inp,   // [8192][1025]
                          const float* __restrict__ h,     // [8192][1024]
                          const float* __restrict__ Wl,    // [4096][2048]
                          const float* __restrict__ Wd,    // [1024][1024]
                          unsigned short* __restrict__ comb, // [8192][2048]
                          unsigned short* __restrict__ Wlb,  // [4096][2048]
                          unsigned short* __restrict__ hb,   // [8192][1024]
                          unsigned short* __restrict__ Wdb,  // [1024][1024]
                          float* __restrict__ Tm1) {         // [8192] = T-1
  const long stride = (long)gridDim.x * blockDim.x;
  const long tid0 = (long)blockIdx.x * blockDim.x + threadIdx.x;

#define CNV8(dst, s0, s1) { ushort4 u0, u1;                                   \
    u0.x = f2bf(s0.x); u0.y = f2bf(s0.y); u0.z = f2bf(s0.z); u0.w = f2bf(s0.w); \
    u1.x = f2bf(s1.x); u1.y = f2bf(s1.y); u1.z = f2bf(s1.z); u1.w = f2bf(s1.w); \
    *(ushort4*)(dst) = u0; *(ushort4*)((dst) + 4) = u1; }

  for (long i = tid0; i < (long)B_ROWS * HSZ / 8; i += stride) {
    float4 v0 = ((const float4*)h)[i * 2], v1 = ((const float4*)h)[i * 2 + 1];
    CNV8(hb + i * 8, v0, v1);
  }
  for (long i = tid0; i < (long)B_ROWS * HSZ / 8; i += stride) {
    long e = i * 8; long b = e >> 10; long c = e & 1023;
    const float* s = inp + b * 1025 + c;
    float4 v0 = *(const float4*)s, v1 = *(const float4*)(s + 4);
    CNV8(comb + b * 2048 + c, v0, v1);
  }
  for (long i = tid0; i < 4096L * 2048 / 8; i += stride) {
    float4 v0 = ((const float4*)Wl)[i * 2], v1 = ((const float4*)Wl)[i * 2 + 1];
    CNV8(Wlb + i * 8, v0, v1);
  }
  for (long i = tid0; i < 1024L * 1024 / 8; i += stride) {
    float4 v0 = ((const float4*)Wd)[i * 2], v1 = ((const float4*)Wd)[i * 2 + 1];
    CNV8(Wdb + i * 8, v0, v1);
  }
  for (long i = tid0; i < B_ROWS; i += stride) {
    float dt = inp[i * 1025 + 1024];
    Tm1[i] = 1.0f / logf(dt + 2.7183f) - 1.0f;
  }
#undef CNV8
}

// ---------- kernel 1: C_ST GEMM (8192x1024x1024) + h_adj epilogue (known-good R3) ----------
__global__ void k_gemm1(const unsigned short* __restrict__ A,   // hb  [8192][1024]
                        const unsigned short* __restrict__ Bm,  // Wdb [1024][1024]
                        const float* __restrict__ h,            // h_cur f32
                        const float* __restrict__ bd,           // b_desc [1024]
                        const float* __restrict__ Tm1,
                        unsigned short* __restrict__ comb) {
  const int K = 1024;
  __shared__ __align__(16) unsigned short As[128 * 32];
  __shared__ __align__(16) unsigned short Bs[128 * 32];
  const int tid = threadIdx.x;
  const int lane = tid & 63;
  const int wave = tid >> 6;
  const int wr = wave >> 1, wc = wave & 1;
  const int bRow = blockIdx.x;    // 0..63
  const int bCol = blockIdx.y;    // 0..7

  const int sRow = tid >> 2;
  const int sK = (tid & 3) * 8;
  const unsigned short* aSrc0 = A + (long)(bRow * 128 + sRow) * K + sK;
  const unsigned short* aSrc1 = A + (long)(bRow * 128 + 64 + sRow) * K + sK;
  const unsigned short* bSrc0 = Bm + (long)(bCol * 128 + sRow) * K + sK;
  const unsigned short* bSrc1 = Bm + (long)(bCol * 128 + 64 + sRow) * K + sK;
  unsigned short* aDst0 = As + tid * 8;
  unsigned short* aDst1 = As + 2048 + tid * 8;
  unsigned short* bDst0 = Bs + tid * 8;
  unsigned short* bDst1 = Bs + 2048 + tid * 8;

  f32x4 acc[4][4] = {};
  const int fr = lane & 15, fk = (lane >> 4) * 8;

  for (int k0 = 0; k0 < K; k0 += 32) {
    GLOAD16(aSrc0 + k0, aDst0);
    GLOAD16(aSrc1 + k0, aDst1);
    GLOAD16(bSrc0 + k0, bDst0);
    GLOAD16(bSrc1 + k0, bDst1);
    __syncthreads();
    bf16x8 a[4], b[4];
#pragma unroll
    for (int m = 0; m < 4; m++) a[m] = *(const bf16x8*)(As + (wr * 64 + m * 16 + fr) * 32 + fk);
#pragma unroll
    for (int n = 0; n < 4; n++) b[n] = *(const bf16x8*)(Bs + (wc * 64 + n * 16 + fr) * 32 + fk);
#pragma unroll
    for (int m = 0; m < 4; m++)
#pragma unroll
      for (int n = 0; n < 4; n++)
        acc[m][n] = __builtin_amdgcn_mfma_f32_16x16x32_bf16(a[m], b[n], acc[m][n], 0, 0, 0);
    __syncthreads();
  }

  const int cr = (lane >> 4) * 4;
  const int cc = lane & 15;
#pragma unroll
  for (int m = 0; m < 4; m++)
#pragma unroll
    for (int n = 0; n < 4; n++) {
      const int col = bCol * 128 + wc * 64 + n * 16 + cc;
#pragma unroll
      for (int r = 0; r < 4; r++) {
        const int row = bRow * 128 + wr * 64 + m * 16 + cr + r;
        float v = acc[m][n][r] + bd[col];
        float cst = tanhf(v);
        float hadj = h[(long)row * HSZ + col] + Tm1[row] * cst;
        comb[(long)row * 2048 + 1024 + col] = f2bf(hadj);
      }
    }
}

// ---------- kernel 2: gates GEMM, 256x256 block, 4 waves, 128x128 WAVE TILE ----------
// R15: halve LDS-read bytes per FLOP via wave-tile aspect. 4 waves (2Mx2N), each owns
// 128x128 output: per K32-tile 16 ds_read_b128 feed 64 MFMA (vs 12:32 before).
// 1 wave/SIMD, acc[8][8] = 256 VGPR (512 budget at 1 wave/SIMD, launch_bounds(256,1)).
// Free-running R11 schedule: one "memory" vmcnt + one barrier per tile, open region
// {stage t+3 (8 gloads); 16 reads; 64 MFMA}. Ring-4. Ledger: 8 loads/tile ->
// at tile-t head outstanding = 24 -> vmcnt(16) publishes t. Tail 16,8,0.
// B gate-interleave: local row rl -> gate=(rl>>4)&3, j=bCol*64+(rl>>6)*16+(rl&15);
// wave wc reads rows wc*128+n*16+fr -> gate=n&3, j-sub=(wc*2+(n>>2)) -> epilogue fused.
#define NT2 64   // 2048/32
__global__ __launch_bounds__(256, 1)
void k_gemm2_bw(const unsigned short* __restrict__ A,   // comb [8192][2048]
                const unsigned short* __restrict__ Bm,  // Wlb  [4096][2048]
                const float* __restrict__ bl,           // b_layers [4096]
                const float* __restrict__ c_cur,        // f32 [8192][1024]
                float* __restrict__ out) {              // h_next | c_next (f32)
  __shared__ __align__(16) unsigned short lds[4][16384];  // [A 256x32 | B 256x32] / slot

  const int tid = threadIdx.x;
  const int lane = tid & 63;
  const int wid = tid >> 6;         // 0..3
  const int wr = wid >> 1;          // 0..1 : row half (128 rows)
  const int wc = wid & 1;           // 0..1 : col half (128 local cols)

  // L2-aware XCD mapping (R6)
  const int bid = blockIdx.x;
  const int xcd = bid & 7;
  const int ii = bid >> 3;
  const int sweep = ii >> 5;
  const int pos = ii & 31;
  const int bRow = xcd * 4 + sweep * 2 + (pos & 1);   // 0..31
  const int bCol = pos >> 1;                          // 0..15

  // ---- staging: 256 threads x 8 gloads/tile (4 A + 4 B row-groups of 64) ----
  const int sr = tid >> 2;               // 0..63
  const int swsel = (sr >> 1) & 3;
  const int gk = ((tid & 3) ^ swsel) << 3;
  const unsigned short* aS0 = A + (long)(bRow * 256 +   0 + sr) * 2048 + gk;
  const unsigned short* aS1 = A + (long)(bRow * 256 +  64 + sr) * 2048 + gk;
  const unsigned short* aS2 = A + (long)(bRow * 256 + 128 + sr) * 2048 + gk;
  const unsigned short* aS3 = A + (long)(bRow * 256 + 192 + sr) * 2048 + gk;
#define GROWF(rl) (((rl) >> 4 & 3) * 1024 + bCol * 64 + ((rl) >> 6) * 16 + ((rl) & 15))
  const unsigned short* bS0 = Bm + (long)GROWF(0   + sr) * 2048 + gk;
  const unsigned short* bS1 = Bm + (long)GROWF(64  + sr) * 2048 + gk;
  const unsigned short* bS2 = Bm + (long)GROWF(128 + sr) * 2048 + gk;
  const unsigned short* bS3 = Bm + (long)GROWF(192 + sr) * 2048 + gk;
#undef GROWF

#define STG(slot, tt) { unsigned short* d_ = &lds[slot][0] + tid * 8;     \
    GLOAD16(aS0 + (long)(tt) * 32, d_);                                    \
    GLOAD16(aS1 + (long)(tt) * 32, d_ + 2048);                             \
    GLOAD16(aS2 + (long)(tt) * 32, d_ + 4096);                             \
    GLOAD16(aS3 + (long)(tt) * 32, d_ + 6144);                             \
    GLOAD16(bS0 + (long)(tt) * 32, d_ + 8192);                             \
    GLOAD16(bS1 + (long)(tt) * 32, d_ + 10240);                            \
    GLOAD16(bS2 + (long)(tt) * 32, d_ + 12288);                            \
    GLOAD16(bS3 + (long)(tt) * 32, d_ + 14336); }

  // ---- fragment read offsets (swizzled, 16-row-verified family), ushort units ----
  const int fr = lane & 15, q = lane >> 4;
  int offA[8], offB[8];
#pragma unroll
  for (int m = 0; m < 8; m++) {
    const int row = wr * 128 + m * 16 + fr;
    offA[m] = row * 32 + ((q ^ ((row >> 1) & 3)) << 3);
  }
#pragma unroll
  for (int n = 0; n < 8; n++) {
    const int row = wc * 128 + n * 16 + fr;
    offB[n] = 8192 + row * 32 + ((q ^ ((row >> 1) & 3)) << 3);
  }

  f32x4 acc[8][8] = {};   // [m][n]; n -> gate = n&3, j-sub = n>>2

  // ---- prologue: stage tiles 0,1,2 into slots 0,1,2 ----
  STG(0, 0); STG(1, 1); STG(2, 2);

#define BODY(t, SLOT, VM, DOSTAGE)                                                   \
  {                                                                                  \
    asm volatile("s_waitcnt vmcnt(" #VM ")" ::: "memory");                           \
    __builtin_amdgcn_s_barrier();                                                    \
    if (DOSTAGE) STG(((t) + 3) & 3, (t) + 3);                                        \
    const unsigned short* buf = &lds[SLOT][0];                                       \
    bf16x8 aF[8], bF[8];                                                             \
    _Pragma("unroll")                                                                \
    for (int n = 0; n < 8; n++) bF[n] = *(const bf16x8*)(buf + offB[n]);             \
    _Pragma("unroll")                                                                \
    for (int m = 0; m < 8; m++) aF[m] = *(const bf16x8*)(buf + offA[m]);             \
    __builtin_amdgcn_s_setprio(1);                                                   \
    _Pragma("unroll")                                                                \
    for (int m = 0; m < 8; m++)                                                      \
      _Pragma("unroll")                                                              \
      for (int n = 0; n < 8; n++)                                                    \
        acc[m][n] = __builtin_amdgcn_mfma_f32_16x16x32_bf16(aF[m], bF[n], acc[m][n], 0, 0, 0); \
    __builtin_amdgcn_s_setprio(0);                                                   \
  }

  for (int t = 0; t < 60; t += 4) {
    BODY(t,     0, 16, true);
    BODY(t + 1, 1, 16, true);
    BODY(t + 2, 2, 16, true);
    BODY(t + 3, 3, 16, true);
  }
  BODY(60, 0, 16, true);
  BODY(61, 1, 16, false);
  BODY(62, 2, 8,  false);
  BODY(63, 3, 0,  false);
#undef BODY

  // ---- fused LSTM epilogue ----
  const int cr = (lane >> 4) * 4;
  const int cc = lane & 15;
#pragma unroll
  for (int m = 0; m < 8; m++) {
#pragma unroll
    for (int js = 0; js < 2; js++) {
      const int j = bCol * 64 + (wc * 2 + js) * 16 + cc;   // 0..1023
      const float b0 = bl[j], b1 = bl[1024 + j], b2 = bl[2048 + j], b3 = bl[3072 + j];
#pragma unroll
      for (int r = 0; r < 4; r++) {
        const int row = bRow * 256 + wr * 128 + m * 16 + cr + r;
        float iv = sigm(acc[m][js * 4 + 0][r] + b0);
        float fv = sigm(acc[m][js * 4 + 1][r] + b1);
        float ov = sigm(acc[m][js * 4 + 2][r] + b2);
        float gv = tanhf(acc[m][js * 4 + 3][r] + b3);
        float cn = fv * c_cur[(long)row * HSZ + j] + iv * gv;
        float hn = ov * tanhf(cn);
        out[(long)row * HSZ + j] = hn;                         // h_next
        out[(long)B_ROWS * HSZ + (long)row * HSZ + j] = cn;    // c_next
      }
    }
  }
}

// ---------- launch ----------
extern "C" void kernel_launch(void* const* d_in, const int* in_sizes, int n_in,
                              void* d_out, int out_size, void* d_ws, size_t ws_size,
                              hipStream_t stream) {
  const float* inp = (const float*)d_in[0];   // input_tensor [8192][1025]
  const float* h   = (const float*)d_in[1];   // h_cur
  const float* c   = (const float*)d_in[2];   // c_cur
  const float* Wl  = (const float*)d_in[3];   // W_layers [4096][2048]
  const float* bl  = (const float*)d_in[4];   // b_layers [4096]
  const float* Wd  = (const float*)d_in[5];   // W_desc [1024][1024]
  const float* bd  = (const float*)d_in[6];   // b_desc [1024]

  char* ws = (char*)d_ws;
  unsigned short* comb = (unsigned short*)(ws);               // 33,554,432 B
  unsigned short* Wlb  = (unsigned short*)(ws + 33554432);    // 16,777,216 B
  unsigned short* hb   = (unsigned short*)(ws + 50331648);    // 16,777,216 B
  unsigned short* Wdb  = (unsigned short*)(ws + 67108864);    //  2,097,152 B
  float*          Tm1  = (float*)(ws + 69206016);             //     32,768 B
  float*          out  = (float*)d_out;                       // f32 outputs

  hipLaunchKernelGGL(k_convert, dim3(2048), dim3(256), 0, stream,
                     inp, h, Wl, Wd, comb, Wlb, hb, Wdb, Tm1);
  hipLaunchKernelGGL(k_gemm1, dim3(64, 8), dim3(256), 0, stream,
                     hb, Wdb, h, bd, Tm1, comb);
  hipLaunchKernelGGL(k_gemm2_bw, dim3(512), dim3(256), 0, stream,
                     comb, Wlb, bl, c, out);
}

// Round 16
// 227.791 us; speedup vs baseline: 1.1190x; 1.1190x over previous
//
#include <hip/hip_runtime.h>
#include <hip/hip_bf16.h>
#include <math.h>

// ---------- types ----------
typedef __bf16 bf16x8 __attribute__((ext_vector_type(8)));
typedef float  f32x4  __attribute__((ext_vector_type(4)));

#define B_ROWS 8192
#define HSZ    1024

#define GLOAD16(gsrc, ldst)                                                          \
  __builtin_amdgcn_global_load_lds((const __attribute__((address_space(1))) void*)(gsrc), \
                                   (__attribute__((address_space(3))) void*)(ldst),  \
                                   16, 0, 0)

__device__ inline unsigned short f2bf(float f) {
  union { float f; unsigned u; } x; x.f = f;
  unsigned r = x.u + 0x7fffu + ((x.u >> 16) & 1u);   // RNE
  return (unsigned short)(r >> 16);
}

__device__ inline float sigm(float x) { return 1.0f / (1.0f + __expf(-x)); }

// ---------- kernel 0: fp32 -> bf16 conversion + T precompute (16B stores) ----------
__global__ void k_convert(const float* __restrict__ inp,   // [8192][1025]
                          const float* __restrict__ h,     // [8192][1024]
                          const float* __restrict__ Wl,    // [4096][2048]
                          const float* __restrict__ Wd,    // [1024][1024]
                          unsigned short* __restrict__ comb, // [8192][2048]
                          unsigned short* __restrict__ Wlb,  // [4096][2048]
                          unsigned short* __restrict__ hb,   // [8192][1024]
                          unsigned short* __restrict__ Wdb,  // [1024][1024]
                          float* __restrict__ Tm1) {         // [8192] = T-1
  const long stride = (long)gridDim.x * blockDim.x;
  const long tid0 = (long)blockIdx.x * blockDim.x + threadIdx.x;

#define CNV8(dst, s0, s1) { ushort4 u0, u1;                                   \
    u0.x = f2bf(s0.x); u0.y = f2bf(s0.y); u0.z = f2bf(s0.z); u0.w = f2bf(s0.w); \
    u1.x = f2bf(s1.x); u1.y = f2bf(s1.y); u1.z = f2bf(s1.z); u1.w = f2bf(s1.w); \
    *(ushort4*)(dst) = u0; *(ushort4*)((dst) + 4) = u1; }

  for (long i = tid0; i < (long)B_ROWS * HSZ / 8; i += stride) {
    float4 v0 = ((const float4*)h)[i * 2], v1 = ((const float4*)h)[i * 2 + 1];
    CNV8(hb + i * 8, v0, v1);
  }
  for (long i = tid0; i < (long)B_ROWS * HSZ / 8; i += stride) {
    long e = i * 8; long b = e >> 10; long c = e & 1023;
    const float* s = inp + b * 1025 + c;
    float4 v0 = *(const float4*)s, v1 = *(const float4*)(s + 4);
    CNV8(comb + b * 2048 + c, v0, v1);
  }
  for (long i = tid0; i < 4096L * 2048 / 8; i += stride) {
    float4 v0 = ((const float4*)Wl)[i * 2], v1 = ((const float4*)Wl)[i * 2 + 1];
    CNV8(Wlb + i * 8, v0, v1);
  }
  for (long i = tid0; i < 1024L * 1024 / 8; i += stride) {
    float4 v0 = ((const float4*)Wd)[i * 2], v1 = ((const float4*)Wd)[i * 2 + 1];
    CNV8(Wdb + i * 8, v0, v1);
  }
  for (long i = tid0; i < B_ROWS; i += stride) {
    float dt = inp[i * 1025 + 1024];
    Tm1[i] = 1.0f / logf(dt + 2.7183f) - 1.0f;
  }
#undef CNV8
}

// ---------- kernel 1: C_ST GEMM (8192x1024x1024) + h_adj epilogue (known-good R3) ----------
__global__ void k_gemm1(const unsigned short* __restrict__ A,   // hb  [8192][1024]
                        const unsigned short* __restrict__ Bm,  // Wdb [1024][1024]
                        const float* __restrict__ h,            // h_cur f32
                        const float* __restrict__ bd,           // b_desc [1024]
                        const float* __restrict__ Tm1,
                        unsigned short* __restrict__ comb) {
  const int K = 1024;
  __shared__ __align__(16) unsigned short As[128 * 32];
  __shared__ __align__(16) unsigned short Bs[128 * 32];
  const int tid = threadIdx.x;
  const int lane = tid & 63;
  const int wave = tid >> 6;
  const int wr = wave >> 1, wc = wave & 1;
  const int bRow = blockIdx.x;    // 0..63
  const int bCol = blockIdx.y;    // 0..7

  const int sRow = tid >> 2;
  const int sK = (tid & 3) * 8;
  const unsigned short* aSrc0 = A + (long)(bRow * 128 + sRow) * K + sK;
  const unsigned short* aSrc1 = A + (long)(bRow * 128 + 64 + sRow) * K + sK;
  const unsigned short* bSrc0 = Bm + (long)(bCol * 128 + sRow) * K + sK;
  const unsigned short* bSrc1 = Bm + (long)(bCol * 128 + 64 + sRow) * K + sK;
  unsigned short* aDst0 = As + tid * 8;
  unsigned short* aDst1 = As + 2048 + tid * 8;
  unsigned short* bDst0 = Bs + tid * 8;
  unsigned short* bDst1 = Bs + 2048 + tid * 8;

  f32x4 acc[4][4] = {};
  const int fr = lane & 15, fk = (lane >> 4) * 8;

  for (int k0 = 0; k0 < K; k0 += 32) {
    GLOAD16(aSrc0 + k0, aDst0);
    GLOAD16(aSrc1 + k0, aDst1);
    GLOAD16(bSrc0 + k0, bDst0);
    GLOAD16(bSrc1 + k0, bDst1);
    __syncthreads();
    bf16x8 a[4], b[4];
#pragma unroll
    for (int m = 0; m < 4; m++) a[m] = *(const bf16x8*)(As + (wr * 64 + m * 16 + fr) * 32 + fk);
#pragma unroll
    for (int n = 0; n < 4; n++) b[n] = *(const bf16x8*)(Bs + (wc * 64 + n * 16 + fr) * 32 + fk);
#pragma unroll
    for (int m = 0; m < 4; m++)
#pragma unroll
      for (int n = 0; n < 4; n++)
        acc[m][n] = __builtin_amdgcn_mfma_f32_16x16x32_bf16(a[m], b[n], acc[m][n], 0, 0, 0);
    __syncthreads();
  }

  const int cr = (lane >> 4) * 4;
  const int cc = lane & 15;
#pragma unroll
  for (int m = 0; m < 4; m++)
#pragma unroll
    for (int n = 0; n < 4; n++) {
      const int col = bCol * 128 + wc * 64 + n * 16 + cc;
#pragma unroll
      for (int r = 0; r < 4; r++) {
        const int row = bRow * 128 + wr * 64 + m * 16 + cr + r;
        float v = acc[m][n][r] + bd[col];
        float cst = tanhf(v);
        float hadj = h[(long)row * HSZ + col] + Tm1[row] * cst;
        comb[(long)row * 2048 + 1024 + col] = f2bf(hadj);
      }
    }
}

// ---------- kernel 2: gates GEMM, 256x256, ring-4, REGISTER-PREFETCH pipeline ----------
// R16: MFMA(t) runs entirely from registers loaded during tile t-1 — no lgkm
// dependence inside the MFMA burst. Per tile: {counted vmcnt(4) "memory" fence;
// barrier (publishes tile t+1 LDS); issue 12 ds_reads of t+1 -> next reg set;
// stage t+3 (4 gloads); 32 MFMA on current reg set}. Reads of t+1 complete UNDER
// the MFMA burst (compiler counted lgkm waits, never a drain).
// Ledger: at fence of tile t outstanding = stages {t+1,t+2} = 8 -> vmcnt(4)
// publishes t+1 exactly. Tail: vmcnt(0) at t=62. Ring-4: stage(t+3)->slot(t-1),
// whose reads completed before MFMA(t-1) < barrier(t) < stage issue. Race-free.
// Reg rotation by 2-tile unroll with named sets (aC/bC vs aN/bN).
#define NT2 64   // 2048/32
__global__ __launch_bounds__(512, 2)
void k_gemm2_rp(const unsigned short* __restrict__ A,   // comb [8192][2048]
                const unsigned short* __restrict__ Bm,  // Wlb  [4096][2048]
                const float* __restrict__ bl,           // b_layers [4096]
                const float* __restrict__ c_cur,        // f32 [8192][1024]
                float* __restrict__ out) {              // h_next | c_next (f32)
  __shared__ __align__(16) unsigned short lds[4][16384];

  const int tid = threadIdx.x;
  const int lane = tid & 63;
  const int wid = tid >> 6;
  const int wr = wid >> 2;          // 0..1 : row half (128 rows)
  const int wc = wid & 3;           // 0..3 : col quarter (16 j x 4 gates)

  // L2-aware XCD mapping (R6)
  const int bid = blockIdx.x;
  const int xcd = bid & 7;
  const int ii = bid >> 3;
  const int sweep = ii >> 5;
  const int pos = ii & 31;
  const int bRow = xcd * 4 + sweep * 2 + (pos & 1);   // 0..31
  const int bCol = pos >> 1;                          // 0..15

  // ---- staging addresses (pre-swizzled global source; LDS dest linear) ----
  const int sr = tid >> 2;                 // 0..127
  const int swsel = (sr >> 1) & 3;
  const int gk = ((tid & 3) ^ swsel) << 3;
  const unsigned short* aBase = A + (long)(bRow * 256 + sr) * 2048 + gk;
  const int rl0 = sr, rl1 = 128 + sr;
  const int grow0 = ((rl0 >> 4) & 3) * 1024 + bCol * 64 + (rl0 >> 6) * 16 + (rl0 & 15);
  const int grow1 = ((rl1 >> 4) & 3) * 1024 + bCol * 64 + (rl1 >> 6) * 16 + (rl1 & 15);
  const unsigned short* bBase0 = Bm + (long)grow0 * 2048 + gk;
  const unsigned short* bBase1 = Bm + (long)grow1 * 2048 + gk;

#define STAGE_A2(slot, tt) { unsigned short* d_ = &lds[slot][0] + tid * 8;        \
    GLOAD16(aBase + (long)(tt) * 32, d_);                                          \
    GLOAD16(aBase + 128L * 2048 + (long)(tt) * 32, d_ + 512 * 8); }
#define STAGE_B2(slot, tt) { unsigned short* d_ = &lds[slot][8192] + tid * 8;     \
    GLOAD16(bBase0 + (long)(tt) * 32, d_);                                         \
    GLOAD16(bBase1 + (long)(tt) * 32, d_ + 512 * 8); }

  // ---- fragment read offsets (swizzled, 16-row-verified family), ushort units ----
  const int fr = lane & 15, q = lane >> 4;
  int offA[8], offB[4];
#pragma unroll
  for (int m = 0; m < 8; m++) {
    const int row = wr * 128 + m * 16 + fr;
    offA[m] = row * 32 + ((q ^ ((row >> 1) & 3)) << 3);
  }
#pragma unroll
  for (int n = 0; n < 4; n++) {
    const int row = wc * 64 + n * 16 + fr;
    offB[n] = 8192 + row * 32 + ((q ^ ((row >> 1) & 3)) << 3);
  }

  f32x4 acc[8][4] = {};            // [m][gate]
  bf16x8 aC[8], bC[4], aN[8], bN[4];   // current / next register sets

  // ---- prologue: stage tiles 0,1,2; publish tile 0; load tile-0 frags -> cur ----
  STAGE_A2(0, 0); STAGE_B2(0, 0);
  STAGE_A2(1, 1); STAGE_B2(1, 1);
  STAGE_A2(2, 2); STAGE_B2(2, 2);
  asm volatile("s_waitcnt vmcnt(8)" ::: "memory");   // oldest 4 = tile 0
  __builtin_amdgcn_s_barrier();
#pragma unroll
  for (int n = 0; n < 4; n++) bC[n] = *(const bf16x8*)(&lds[0][0] + offB[n]);
#pragma unroll
  for (int m = 0; m < 8; m++) aC[m] = *(const bf16x8*)(&lds[0][0] + offA[m]);

  // TILE(t, CUR..., NXT..., VM, DOREAD, DOSTAGE)
#define TILE(t, aCur, bCur, aNxt, bNxt, VM, DOREAD, DOSTAGE)                         \
  {                                                                                  \
    asm volatile("s_waitcnt vmcnt(" #VM ")" ::: "memory");                           \
    __builtin_amdgcn_s_barrier();                                                    \
    if (DOREAD) {                                                                    \
      const unsigned short* bufN = &lds[((t) + 1) & 3][0];                           \
      _Pragma("unroll")                                                              \
      for (int n = 0; n < 4; n++) bNxt[n] = *(const bf16x8*)(bufN + offB[n]);        \
      _Pragma("unroll")                                                              \
      for (int m = 0; m < 8; m++) aNxt[m] = *(const bf16x8*)(bufN + offA[m]);        \
    }                                                                                \
    if (DOSTAGE) { STAGE_A2(((t) + 3) & 3, (t) + 3); STAGE_B2(((t) + 3) & 3, (t) + 3); } \
    __builtin_amdgcn_s_setprio(1);                                                   \
    _Pragma("unroll")                                                                \
    for (int m = 0; m < 8; m++)                                                      \
      _Pragma("unroll")                                                              \
      for (int n = 0; n < 4; n++)                                                    \
        acc[m][n] = __builtin_amdgcn_mfma_f32_16x16x32_bf16(aCur[m], bCur[n], acc[m][n], 0, 0, 0); \
    __builtin_amdgcn_s_setprio(0);                                                   \
  }

  for (int t = 0; t < 60; t += 2) {
    TILE(t,     aC, bC, aN, bN, 4, true, true);
    TILE(t + 1, aN, bN, aC, bC, 4, true, true);
  }
  TILE(60, aC, bC, aN, bN, 4, true,  true);    // stages 63, reads 61
  TILE(61, aN, bN, aC, bC, 4, true,  false);   // reads 62
  TILE(62, aC, bC, aN, bN, 0, true,  false);   // reads 63 (needs stage 63 done)
  TILE(63, aN, bN, aC, bC, 0, false, false);   // MFMA only
#undef TILE

  // ---- fused LSTM epilogue ----
  const int cr = (lane >> 4) * 4;
  const int cc = lane & 15;
  const int j = bCol * 64 + wc * 16 + cc;       // 0..1023
#pragma unroll
  for (int m = 0; m < 8; m++) {
#pragma unroll
    for (int r = 0; r < 4; r++) {
      const int row = bRow * 256 + wr * 128 + m * 16 + cr + r;
      float iv = sigm(acc[m][0][r] + bl[j]);
      float fv = sigm(acc[m][1][r] + bl[1024 + j]);
      float ov = sigm(acc[m][2][r] + bl[2048 + j]);
      float gv = tanhf(acc[m][3][r] + bl[3072 + j]);
      float cn = fv * c_cur[(long)row * HSZ + j] + iv * gv;
      float hn = ov * tanhf(cn);
      out[(long)row * HSZ + j] = hn;                         // h_next
      out[(long)B_ROWS * HSZ + (long)row * HSZ + j] = cn;    // c_next
    }
  }
}

// ---------- launch ----------
extern "C" void kernel_launch(void* const* d_in, const int* in_sizes, int n_in,
                              void* d_out, int out_size, void* d_ws, size_t ws_size,
                              hipStream_t stream) {
  const float* inp = (const float*)d_in[0];   // input_tensor [8192][1025]
  const float* h   = (const float*)d_in[1];   // h_cur
  const float* c   = (const float*)d_in[2];   // c_cur
  const float* Wl  = (const float*)d_in[3];   // W_layers [4096][2048]
  const float* bl  = (const float*)d_in[4];   // b_layers [4096]
  const float* Wd  = (const float*)d_in[5];   // W_desc [1024][1024]
  const float* bd  = (const float*)d_in[6];   // b_desc [1024]

  char* ws = (char*)d_ws;
  unsigned short* comb = (unsigned short*)(ws);               // 33,554,432 B
  unsigned short* Wlb  = (unsigned short*)(ws + 33554432);    // 16,777,216 B
  unsigned short* hb   = (unsigned short*)(ws + 50331648);    // 16,777,216 B
  unsigned short* Wdb  = (unsigned short*)(ws + 67108864);    //  2,097,152 B
  float*          Tm1  = (float*)(ws + 69206016);             //     32,768 B
  float*          out  = (float*)d_out;                       // f32 outputs

  hipLaunchKernelGGL(k_convert, dim3(2048), dim3(256), 0, stream,
                     inp, h, Wl, Wd, comb, Wlb, hb, Wdb, Tm1);
  hipLaunchKernelGGL(k_gemm1, dim3(64, 8), dim3(256), 0, stream,
                     hb, Wdb, h, bd, Tm1, comb);
  hipLaunchKernelGGL(k_gemm2_rp, dim3(512), dim3(512), 0, stream,
                     comb, Wlb, bl, c, out);
}

// Round 17
// 224.616 us; speedup vs baseline: 1.1348x; 1.0141x over previous
//
#include <hip/hip_runtime.h>
#include <hip/hip_bf16.h>
#include <math.h>

// ---------- types ----------
typedef __bf16 bf16x8 __attribute__((ext_vector_type(8)));
typedef float  f32x4  __attribute__((ext_vector_type(4)));

#define B_ROWS 8192
#define HSZ    1024

#define GLOAD16(gsrc, ldst)                                                          \
  __builtin_amdgcn_global_load_lds((const __attribute__((address_space(1))) void*)(gsrc), \
                                   (__attribute__((address_space(3))) void*)(ldst),  \
                                   16, 0, 0)

__device__ inline unsigned short f2bf(float f) {
  union { float f; unsigned u; } x; x.f = f;
  unsigned r = x.u + 0x7fffu + ((x.u >> 16) & 1u);   // RNE
  return (unsigned short)(r >> 16);
}

__device__ inline float sigm(float x) { return 1.0f / (1.0f + __expf(-x)); }

// ---------- kernel 0: fp32 -> bf16 conversion + T precompute (16B stores) ----------
__global__ void k_convert(const float* __restrict__ inp,   // [8192][1025]
                          const float* __restrict__ h,     // [8192][1024]
                          const float* __restrict__ Wl,    // [4096][2048]
                          const float* __restrict__ Wd,    // [1024][1024]
                          unsigned short* __restrict__ comb, // [8192][2048]
                          unsigned short* __restrict__ Wlb,  // [4096][2048]
                          unsigned short* __restrict__ hb,   // [8192][1024]
                          unsigned short* __restrict__ Wdb,  // [1024][1024]
                          float* __restrict__ Tm1) {         // [8192] = T-1
  const long stride = (long)gridDim.x * blockDim.x;
  const long tid0 = (long)blockIdx.x * blockDim.x + threadIdx.x;

#define CNV8(dst, s0, s1) { ushort4 u0, u1;                                   \
    u0.x = f2bf(s0.x); u0.y = f2bf(s0.y); u0.z = f2bf(s0.z); u0.w = f2bf(s0.w); \
    u1.x = f2bf(s1.x); u1.y = f2bf(s1.y); u1.z = f2bf(s1.z); u1.w = f2bf(s1.w); \
    *(ushort4*)(dst) = u0; *(ushort4*)((dst) + 4) = u1; }

  for (long i = tid0; i < (long)B_ROWS * HSZ / 8; i += stride) {
    float4 v0 = ((const float4*)h)[i * 2], v1 = ((const float4*)h)[i * 2 + 1];
    CNV8(hb + i * 8, v0, v1);
  }
  for (long i = tid0; i < (long)B_ROWS * HSZ / 8; i += stride) {
    long e = i * 8; long b = e >> 10; long c = e & 1023;
    const float* s = inp + b * 1025 + c;
    float4 v0 = *(const float4*)s, v1 = *(const float4*)(s + 4);
    CNV8(comb + b * 2048 + c, v0, v1);
  }
  for (long i = tid0; i < 4096L * 2048 / 8; i += stride) {
    float4 v0 = ((const float4*)Wl)[i * 2], v1 = ((const float4*)Wl)[i * 2 + 1];
    CNV8(Wlb + i * 8, v0, v1);
  }
  for (long i = tid0; i < 1024L * 1024 / 8; i += stride) {
    float4 v0 = ((const float4*)Wd)[i * 2], v1 = ((const float4*)Wd)[i * 2 + 1];
    CNV8(Wdb + i * 8, v0, v1);
  }
  for (long i = tid0; i < B_ROWS; i += stride) {
    float dt = inp[i * 1025 + 1024];
    Tm1[i] = 1.0f / logf(dt + 2.7183f) - 1.0f;
  }
#undef CNV8
}

// ---------- kernel 1: C_ST GEMM (8192x1024x1024) + h_adj epilogue (known-good R3) ----------
__global__ void k_gemm1(const unsigned short* __restrict__ A,   // hb  [8192][1024]
                        const unsigned short* __restrict__ Bm,  // Wdb [1024][1024]
                        const float* __restrict__ h,            // h_cur f32
                        const float* __restrict__ bd,           // b_desc [1024]
                        const float* __restrict__ Tm1,
                        unsigned short* __restrict__ comb) {
  const int K = 1024;
  __shared__ __align__(16) unsigned short As[128 * 32];
  __shared__ __align__(16) unsigned short Bs[128 * 32];
  const int tid = threadIdx.x;
  const int lane = tid & 63;
  const int wave = tid >> 6;
  const int wr = wave >> 1, wc = wave & 1;
  const int bRow = blockIdx.x;    // 0..63
  const int bCol = blockIdx.y;    // 0..7

  const int sRow = tid >> 2;
  const int sK = (tid & 3) * 8;
  const unsigned short* aSrc0 = A + (long)(bRow * 128 + sRow) * K + sK;
  const unsigned short* aSrc1 = A + (long)(bRow * 128 + 64 + sRow) * K + sK;
  const unsigned short* bSrc0 = Bm + (long)(bCol * 128 + sRow) * K + sK;
  const unsigned short* bSrc1 = Bm + (long)(bCol * 128 + 64 + sRow) * K + sK;
  unsigned short* aDst0 = As + tid * 8;
  unsigned short* aDst1 = As + 2048 + tid * 8;
  unsigned short* bDst0 = Bs + tid * 8;
  unsigned short* bDst1 = Bs + 2048 + tid * 8;

  f32x4 acc[4][4] = {};
  const int fr = lane & 15, fk = (lane >> 4) * 8;

  for (int k0 = 0; k0 < K; k0 += 32) {
    GLOAD16(aSrc0 + k0, aDst0);
    GLOAD16(aSrc1 + k0, aDst1);
    GLOAD16(bSrc0 + k0, bDst0);
    GLOAD16(bSrc1 + k0, bDst1);
    __syncthreads();
    bf16x8 a[4], b[4];
#pragma unroll
    for (int m = 0; m < 4; m++) a[m] = *(const bf16x8*)(As + (wr * 64 + m * 16 + fr) * 32 + fk);
#pragma unroll
    for (int n = 0; n < 4; n++) b[n] = *(const bf16x8*)(Bs + (wc * 64 + n * 16 + fr) * 32 + fk);
#pragma unroll
    for (int m = 0; m < 4; m++)
#pragma unroll
      for (int n = 0; n < 4; n++)
        acc[m][n] = __builtin_amdgcn_mfma_f32_16x16x32_bf16(a[m], b[n], acc[m][n], 0, 0, 0);
    __syncthreads();
  }

  const int cr = (lane >> 4) * 4;
  const int cc = lane & 15;
#pragma unroll
  for (int m = 0; m < 4; m++)
#pragma unroll
    for (int n = 0; n < 4; n++) {
      const int col = bCol * 128 + wc * 64 + n * 16 + cc;
#pragma unroll
      for (int r = 0; r < 4; r++) {
        const int row = bRow * 128 + wr * 64 + m * 16 + cr + r;
        float v = acc[m][n][r] + bd[col];
        float cst = tanhf(v);
        float hadj = h[(long)row * HSZ + col] + Tm1[row] * cst;
        comb[(long)row * 2048 + 1024 + col] = f2bf(hadj);
      }
    }
}

// ---------- kernel 2: gates GEMM, 256x256, ring-4, reg-prefetch, NO SETPRIO ----------
// R17 single-variable A/B vs R16: all s_setprio removed. Theory: setprio(1) around
// the 32-MFMA burst starves the sibling wave's ds_read/DMA issue on the shared SIMD
// (priority preference even when matrix pipe busy), serializing the two waves ->
// ~2x1242 cy/tile observed. T5 doc: setprio is 0/negative on lockstep GEMM (m190).
// Everything else identical to R16 (best measured: 174.5 us, 35.1% MfmaUtil).
#define NT2 64   // 2048/32
__global__ __launch_bounds__(512, 2)
void k_gemm2_np(const unsigned short* __restrict__ A,   // comb [8192][2048]
                const unsigned short* __restrict__ Bm,  // Wlb  [4096][2048]
                const float* __restrict__ bl,           // b_layers [4096]
                const float* __restrict__ c_cur,        // f32 [8192][1024]
                float* __restrict__ out) {              // h_next | c_next (f32)
  __shared__ __align__(16) unsigned short lds[4][16384];

  const int tid = threadIdx.x;
  const int lane = tid & 63;
  const int wid = tid >> 6;
  const int wr = wid >> 2;          // 0..1 : row half (128 rows)
  const int wc = wid & 3;           // 0..3 : col quarter (16 j x 4 gates)

  // L2-aware XCD mapping (R6)
  const int bid = blockIdx.x;
  const int xcd = bid & 7;
  const int ii = bid >> 3;
  const int sweep = ii >> 5;
  const int pos = ii & 31;
  const int bRow = xcd * 4 + sweep * 2 + (pos & 1);   // 0..31
  const int bCol = pos >> 1;                          // 0..15

  // ---- staging addresses (pre-swizzled global source; LDS dest linear) ----
  const int sr = tid >> 2;                 // 0..127
  const int swsel = (sr >> 1) & 3;
  const int gk = ((tid & 3) ^ swsel) << 3;
  const unsigned short* aBase = A + (long)(bRow * 256 + sr) * 2048 + gk;
  const int rl0 = sr, rl1 = 128 + sr;
  const int grow0 = ((rl0 >> 4) & 3) * 1024 + bCol * 64 + (rl0 >> 6) * 16 + (rl0 & 15);
  const int grow1 = ((rl1 >> 4) & 3) * 1024 + bCol * 64 + (rl1 >> 6) * 16 + (rl1 & 15);
  const unsigned short* bBase0 = Bm + (long)grow0 * 2048 + gk;
  const unsigned short* bBase1 = Bm + (long)grow1 * 2048 + gk;

#define STAGE_A2(slot, tt) { unsigned short* d_ = &lds[slot][0] + tid * 8;        \
    GLOAD16(aBase + (long)(tt) * 32, d_);                                          \
    GLOAD16(aBase + 128L * 2048 + (long)(tt) * 32, d_ + 512 * 8); }
#define STAGE_B2(slot, tt) { unsigned short* d_ = &lds[slot][8192] + tid * 8;     \
    GLOAD16(bBase0 + (long)(tt) * 32, d_);                                         \
    GLOAD16(bBase1 + (long)(tt) * 32, d_ + 512 * 8); }

  // ---- fragment read offsets (swizzled, 16-row-verified family), ushort units ----
  const int fr = lane & 15, q = lane >> 4;
  int offA[8], offB[4];
#pragma unroll
  for (int m = 0; m < 8; m++) {
    const int row = wr * 128 + m * 16 + fr;
    offA[m] = row * 32 + ((q ^ ((row >> 1) & 3)) << 3);
  }
#pragma unroll
  for (int n = 0; n < 4; n++) {
    const int row = wc * 64 + n * 16 + fr;
    offB[n] = 8192 + row * 32 + ((q ^ ((row >> 1) & 3)) << 3);
  }

  f32x4 acc[8][4] = {};            // [m][gate]
  bf16x8 aC[8], bC[4], aN[8], bN[4];   // current / next register sets

  // ---- prologue: stage tiles 0,1,2; publish tile 0; load tile-0 frags -> cur ----
  STAGE_A2(0, 0); STAGE_B2(0, 0);
  STAGE_A2(1, 1); STAGE_B2(1, 1);
  STAGE_A2(2, 2); STAGE_B2(2, 2);
  asm volatile("s_waitcnt vmcnt(8)" ::: "memory");   // oldest 4 = tile 0
  __builtin_amdgcn_s_barrier();
#pragma unroll
  for (int n = 0; n < 4; n++) bC[n] = *(const bf16x8*)(&lds[0][0] + offB[n]);
#pragma unroll
  for (int m = 0; m < 8; m++) aC[m] = *(const bf16x8*)(&lds[0][0] + offA[m]);

  // TILE(t, CUR..., NXT..., VM, DOREAD, DOSTAGE) — NO setprio anywhere.
#define TILE(t, aCur, bCur, aNxt, bNxt, VM, DOREAD, DOSTAGE)                         \
  {                                                                                  \
    asm volatile("s_waitcnt vmcnt(" #VM ")" ::: "memory");                           \
    __builtin_amdgcn_s_barrier();                                                    \
    if (DOREAD) {                                                                    \
      const unsigned short* bufN = &lds[((t) + 1) & 3][0];                           \
      _Pragma("unroll")                                                              \
      for (int n = 0; n < 4; n++) bNxt[n] = *(const bf16x8*)(bufN + offB[n]);        \
      _Pragma("unroll")                                                              \
      for (int m = 0; m < 8; m++) aNxt[m] = *(const bf16x8*)(bufN + offA[m]);        \
    }                                                                                \
    if (DOSTAGE) { STAGE_A2(((t) + 3) & 3, (t) + 3); STAGE_B2(((t) + 3) & 3, (t) + 3); } \
    _Pragma("unroll")                                                                \
    for (int m = 0; m < 8; m++)                                                      \
      _Pragma("unroll")                                                              \
      for (int n = 0; n < 4; n++)                                                    \
        acc[m][n] = __builtin_amdgcn_mfma_f32_16x16x32_bf16(aCur[m], bCur[n], acc[m][n], 0, 0, 0); \
  }

  for (int t = 0; t < 60; t += 2) {
    TILE(t,     aC, bC, aN, bN, 4, true, true);
    TILE(t + 1, aN, bN, aC, bC, 4, true, true);
  }
  TILE(60, aC, bC, aN, bN, 4, true,  true);    // stages 63, reads 61
  TILE(61, aN, bN, aC, bC, 4, true,  false);   // reads 62
  TILE(62, aC, bC, aN, bN, 0, true,  false);   // reads 63 (needs stage 63 done)
  TILE(63, aN, bN, aC, bC, 0, false, false);   // MFMA only
#undef TILE

  // ---- fused LSTM epilogue ----
  const int cr = (lane >> 4) * 4;
  const int cc = lane & 15;
  const int j = bCol * 64 + wc * 16 + cc;       // 0..1023
#pragma unroll
  for (int m = 0; m < 8; m++) {
#pragma unroll
    for (int r = 0; r < 4; r++) {
      const int row = bRow * 256 + wr * 128 + m * 16 + cr + r;
      float iv = sigm(acc[m][0][r] + bl[j]);
      float fv = sigm(acc[m][1][r] + bl[1024 + j]);
      float ov = sigm(acc[m][2][r] + bl[2048 + j]);
      float gv = tanhf(acc[m][3][r] + bl[3072 + j]);
      float cn = fv * c_cur[(long)row * HSZ + j] + iv * gv;
      float hn = ov * tanhf(cn);
      out[(long)row * HSZ + j] = hn;                         // h_next
      out[(long)B_ROWS * HSZ + (long)row * HSZ + j] = cn;    // c_next
    }
  }
}

// ---------- launch ----------
extern "C" void kernel_launch(void* const* d_in, const int* in_sizes, int n_in,
                              void* d_out, int out_size, void* d_ws, size_t ws_size,
                              hipStream_t stream) {
  const float* inp = (const float*)d_in[0];   // input_tensor [8192][1025]
  const float* h   = (const float*)d_in[1];   // h_cur
  const float* c   = (const float*)d_in[2];   // c_cur
  const float* Wl  = (const float*)d_in[3];   // W_layers [4096][2048]
  const float* bl  = (const float*)d_in[4];   // b_layers [4096]
  const float* Wd  = (const float*)d_in[5];   // W_desc [1024][1024]
  const float* bd  = (const float*)d_in[6];   // b_desc [1024]

  char* ws = (char*)d_ws;
  unsigned short* comb = (unsigned short*)(ws);               // 33,554,432 B
  unsigned short* Wlb  = (unsigned short*)(ws + 33554432);    // 16,777,216 B
  unsigned short* hb   = (unsigned short*)(ws + 50331648);    // 16,777,216 B
  unsigned short* Wdb  = (unsigned short*)(ws + 67108864);    //  2,097,152 B
  float*          Tm1  = (float*)(ws + 69206016);             //     32,768 B
  float*          out  = (float*)d_out;                       // f32 outputs

  hipLaunchKernelGGL(k_convert, dim3(2048), dim3(256), 0, stream,
                     inp, h, Wl, Wd, comb, Wlb, hb, Wdb, Tm1);
  hipLaunchKernelGGL(k_gemm1, dim3(64, 8), dim3(256), 0, stream,
                     hb, Wdb, h, bd, Tm1, comb);
  hipLaunchKernelGGL(k_gemm2_np, dim3(512), dim3(512), 0, stream,
                     comb, Wlb, bl, c, out);
}